// Round 12
// baseline (743.443 us; speedup 1.0000x reference)
//
#include <hip/hip_runtime.h>
#include <math.h>

#define B_TOTAL  262144
#define ROWS     64
#define NWG      (B_TOTAL/ROWS)   // 4096
#define NTHR     512
#define PI_F     3.14159265358979323846f
#define NORM_R   (500.0f/150000.0f)

typedef float  f32x4  __attribute__((ext_vector_type(4)));
typedef short  bf16x8 __attribute__((ext_vector_type(8)));

// ws = 49 uniform 16KB slabs (8192 ushorts), pre-swizzled LDS images.
// g: 0-2 gi(kb g) | 3-10 gh(kb g-3) | 11-21 r(kb g-11) | 22-32 z(kb g-22)
//    33-40 W1(kb g-33) | 41-44 W2(2x4096-ushort halves, kb 2(g-41)+h) | 45-48 W3(kb g-45)
#define W_TOTAL (49*8192)

// ---- LDS (bytes) ----
#define LDS_RB   0                 // Rb [64][104]u16 = 13312 (innov live to the end)
#define LDS_HB   13312             // Hb [64][256] bf16 swizzled = 32768: scr->hx->h_new->h_ln->f1->F2
#define LDS_RING 46080             // 8 waves x 12288 (2 bufs x 6KB) wave-private rings
#define LDS_XMC  144384            // [64][6] f32 = 1536
#define LDS_TOTAL 145920

#define WAIT_VM6  asm volatile("s_waitcnt vmcnt(6)" ::: "memory")
#define WAIT_VM2  asm volatile("s_waitcnt vmcnt(2)" ::: "memory")
#define WAIT_VM1  asm volatile("s_waitcnt vmcnt(1)" ::: "memory")
#define WAIT_VM0  asm volatile("s_waitcnt vmcnt(0)" ::: "memory")
#define WAIT_LGKM asm volatile("s_waitcnt lgkmcnt(0)" ::: "memory")

__device__ __forceinline__ ushort f2bf(float f){
    union { float f; unsigned u; } v; v.f = f;
    unsigned r = v.u + 0x7FFFu + ((v.u >> 16) & 1u);
    return (ushort)(r >> 16);
}
__device__ __forceinline__ float b2f(ushort u){
    union { unsigned u; float f; } v; v.u = ((unsigned)u) << 16;
    return v.f;
}
__device__ __forceinline__ unsigned pk2(float a, float b){
    return (unsigned)f2bf(a) | ((unsigned)f2bf(b) << 16);
}
__device__ __forceinline__ float upk(unsigned u, int hi){
    return b2f((ushort)(hi ? (u >> 16) : (u & 0xffffu)));
}
__device__ __forceinline__ float sigm(float x){ return 1.0f/(1.0f+__expf(-x)); }
__device__ __forceinline__ float tanh_(float x){ return 1.0f - 2.0f/(__expf(2.0f*x)+1.0f); }
__device__ __forceinline__ int swzb(int row, int k){     // Hb [*][256] bf16, 16B-XOR
    return ((row<<9) + (k<<1)) ^ ((row&7)<<4);
}
// B-frag from a wave-private chunk: [ncols][4 slots][16B]; cl = local col.
// global col base is a multiple of 8 -> local XOR valid.
__device__ __forceinline__ bf16x8 rdW2(const char* chunk, int cl, int lk){
    int slot = lk ^ ((cl >> 1) & 3);
    return *(const bf16x8*)(chunk + cl*64 + slot*16);
}
// 2KB chunk (32 cols x 64B): 2 gload_lds
__device__ __forceinline__ void stage2k(const ushort* src, char* dst, int lane){
    #pragma unroll
    for (int i = 0; i < 2; ++i)
        __builtin_amdgcn_global_load_lds(
            (const __attribute__((address_space(1))) void*)(src + i*512 + lane*8),
            (__attribute__((address_space(3))) void*)(dst + i*1024),
            16, 0, 0);
}
// 1KB chunk (16 cols x 64B): 1 gload_lds
__device__ __forceinline__ void stage1k(const ushort* src, char* dst, int lane){
    __builtin_amdgcn_global_load_lds(
        (const __attribute__((address_space(1))) void*)(src + lane*8),
        (__attribute__((address_space(3))) void*)(dst),
        16, 0, 0);
}

__device__ __forceinline__ void ldA4_rb(const ushort* Rbu, int lr, int kb, int lk8, bf16x8 a[4]){
    #pragma unroll
    for (int i = 0; i < 4; ++i)
        a[i] = *(const bf16x8*)(Rbu + (i*16 + lr)*104 + kb*32 + lk8);
}
__device__ __forceinline__ void ldA4_hb(const char* Hb, int lr, int kb, int lk8, bf16x8 a[4]){
    #pragma unroll
    for (int i = 0; i < 4; ++i)
        a[i] = *(const bf16x8*)(Hb + swzb(i*16 + lr, kb*32 + lk8));
}

__global__ void prep_weights(const float* __restrict__ W_ih, const float* __restrict__ W_hh,
                             const float* __restrict__ W1, const float* __restrict__ W2,
                             const float* __restrict__ W3, ushort* __restrict__ ws)
{
    int id = blockIdx.x*256 + threadIdx.x;
    if (id >= W_TOTAL) return;
    int g = id >> 13;
    int u = id & 8191;
    float v = 0.0f;
    if (g >= 41 && g < 45) {               // W2: two 4096-ushort halves [128][64B]
        int half = u >> 12, u2 = u & 4095;
        int col = u2 >> 5, v5 = u2 & 31, slot = v5 >> 3, e = v5 & 7;
        int kq = slot ^ ((col >> 1) & 3);
        int kb = (g-41)*2 + half;
        v = W2[col*256 + kb*32 + kq*8 + e];
    } else {
        int col = u >> 5, v5 = u & 31, slot = v5 >> 3, e = v5 & 7;
        int kq = slot ^ ((col >> 1) & 3);
        if (g < 3) {                       // gi
            int k = g*32 + kq*8 + e;
            if (k < 73) v = W_ih[(512+col)*73 + k];
        } else if (g < 11) {               // gh
            int k = (g-3)*32 + kq*8 + e;
            v = W_hh[(512+col)*256 + k];
        } else if (g < 22) {               // r
            int k = (g-11)*32 + kq*8 + e;
            v = (k < 73) ? W_ih[col*73 + k] : ((k < 96) ? 0.0f : W_hh[col*256 + (k-96)]);
        } else if (g < 33) {               // z
            int k = (g-22)*32 + kq*8 + e;
            v = (k < 73) ? W_ih[(256+col)*73 + k] : ((k < 96) ? 0.0f : W_hh[(256+col)*256 + (k-96)]);
        } else if (g < 41) {               // W1
            int k = (g-33)*32 + kq*8 + e;
            v = W1[col*256 + k];
        } else {                           // W3, cols>=162 zero
            int k = (g-45)*32 + kq*8 + e;
            if (col < 162) v = W3[col*128 + k];
        }
    }
    ws[id] = f2bf(v);
}

__global__ __launch_bounds__(NTHR, 2) void knet_mfma(
    const float* __restrict__ meas, const float* __restrict__ mask,
    const float* __restrict__ dt,   const float* __restrict__ baselines,
    const float* __restrict__ x_prev, const float* __restrict__ hx,
    const float* __restrict__ b_ih, const float* __restrict__ b_hh,
    const float* __restrict__ ln_g, const float* __restrict__ ln_b,
    const float* __restrict__ b1,   const float* __restrict__ b2,
    const float* __restrict__ b3,
    const ushort* __restrict__ ws,
    float* __restrict__ out)
{
    extern __shared__ char smem[];
    ushort* Rbu  = (ushort*)(smem + LDS_RB);
    char*   Hb   = smem + LDS_HB;
    float*  xmc  = (float*)(smem + LDS_XMC);

    const int tid  = threadIdx.x;
    const int w    = __builtin_amdgcn_readfirstlane(tid >> 6);   // wave 0..7
    const int lane = tid & 63;
    const int lr   = lane & 15;
    const int lk   = lane >> 4;
    const int lk8  = lk * 8;
    const int cw   = w * 32;          // this wave's output-col base
    const int row0 = blockIdx.x * ROWS;
    char* ring = smem + LDS_RING + w*12288;   // wave-private: 2 bufs x 6KB
    float* hout = out + (size_t)B_TOTAL*6;

    // ---- GRU triple stage: r(11+kb), z(22+kb), g(kb) -> buf ----
    auto issue_triple = [&](int kb, char* buf){
        stage2k(ws + (size_t)(11+kb)*8192 + w*1024, buf,        lane);
        stage2k(ws + (size_t)(22+kb)*8192 + w*1024, buf + 2048, lane);
        stage2k(ws + (size_t)kb*8192      + w*1024, buf + 4096, lane);
    };

    // prologue: GRU kb0, kb1 triples in flight (drained by the pre-loop syncthreads)
    issue_triple(0, ring);
    issue_triple(1, ring + 6144);

    // ---- input staging -> Hb scratch (f32) ----
    float* scr = (float*)Hb;
    {
        const size_t m0 = (size_t)row0*27;
        for (int i = tid; i < 1728; i += NTHR) scr[i]        = meas[m0 + i];
        for (int i = tid; i < 1728; i += NTHR) scr[1728 + i] = mask[m0 + i];
        for (int i = tid; i < 768;  i += NTHR) scr[3456 + i] = baselines[(size_t)row0*12 + i];
        for (int i = tid; i < 384;  i += NTHR) scr[4224 + i] = x_prev[(size_t)row0*6 + i];
        if (tid < 64) scr[4608 + tid] = dt[row0 + tid];
    }
    __syncthreads();

    // ---- geometry: scratch -> Rb, xmc (waves 0..3) ----
    if (w < 4) {
        const int row = lane;
        const float dtv = scr[4608 + row];
        const float dts = dtv * NORM_R;
        float xp[6], xm[6];
        #pragma unroll
        for (int s = 0; s < 6; ++s) xp[s] = scr[4224 + row*6 + s];
        xm[0] = xp[0] + dts*xp[1]; xm[1] = xp[1];
        xm[2] = xp[2] + dts*xp[3]; xm[3] = xp[3];
        xm[4] = xp[4] + dts*xp[5]; xm[5] = xp[5];
        if (w < 3) {
            float xr[6];
            #pragma unroll
            for (int s = 0; s < 6; ++s) {
                float b = (w == 0) ? 0.0f : scr[3456 + row*12 + (w-1)*6 + s];
                xr[s] = xm[s] - b;
            }
            float rxy = sqrtf(xr[0]*xr[0] + xr[2]*xr[2] + 1e-9f);
            float azv = atan2f(xr[2], xr[0]) * (1.0f/PI_F);
            float elv = atan2f(xr[4], rxy)   * (1.0f/PI_F);
            float rrv = sqrtf(xr[0]*xr[0] + xr[2]*xr[2] + xr[4]*xr[4] + 1e-9f);
            float y[9] = {azv, elv, rrv, azv, elv, 0.0f, azv, 0.0f, 0.0f};
            const bool ang[9] = {true,true,false,true,true,false,true,false,false};
            #pragma unroll
            for (int i = 0; i < 9; ++i) {
                int m = w*9 + i;
                float ms = scr[1728 + row*27 + m];
                float v  = scr[row*27 + m] - y[i];
                if (ang[i]) v = v - 2.0f*rintf(v*0.5f);
                v *= ms;
                Rbu[row*104 + m]      = f2bf(v);
                Rbu[row*104 + 27 + m] = f2bf(ms);
            }
        } else {
            Rbu[row*104 + 54] = f2bf(dtv);
            #pragma unroll
            for (int s = 0; s < 6; ++s) Rbu[row*104 + 55 + s] = f2bf(xm[s]);
            #pragma unroll
            for (int q = 0; q < 12; ++q) Rbu[row*104 + 61 + q] = f2bf(scr[3456 + row*12 + q]);
            #pragma unroll
            for (int k = 73; k < 96; ++k) Rbu[row*104 + k] = 0;
            #pragma unroll
            for (int s = 0; s < 6; ++s) xmc[row*6 + s] = xm[s];
        }
    }
    __syncthreads();

    // ---- hx -> Hb (bf16, swizzled) ----
    {
        const size_t hbase = (size_t)row0 * 256;
        #pragma unroll
        for (int ii = 0; ii < 4; ++ii) {
            int cid = tid + ii*NTHR;
            int r  = cid >> 5;
            int k0 = (cid & 31) << 3;
            const float4* p = (const float4*)(hx + hbase + (size_t)r*256 + k0);
            float4 u = p[0], v2 = p[1];
            bf16x8 o;
            o[0]=(short)f2bf(u.x);  o[1]=(short)f2bf(u.y);  o[2]=(short)f2bf(u.z);  o[3]=(short)f2bf(u.w);
            o[4]=(short)f2bf(v2.x); o[5]=(short)f2bf(v2.y); o[6]=(short)f2bf(v2.z); o[7]=(short)f2bf(v2.w);
            *(bf16x8*)(Hb + swzb(r, k0)) = o;
        }
    }
    __syncthreads();   // inputs ready; vmcnt drained (GRU kb0/kb1 resident)

    // ========== GRU: fused r|z|g, barrier-free self-paced K-loop ==========
    f32x4 ar[4][2], az[4][2], ag[4][2];
    unsigned gipk[4][2][2];
    #pragma unroll
    for (int i = 0; i < 4; ++i)
        #pragma unroll
        for (int j = 0; j < 2; ++j) { ar[i][j]=(f32x4){0,0,0,0}; az[i][j]=(f32x4){0,0,0,0}; ag[i][j]=(f32x4){0,0,0,0}; }

    #pragma unroll
    for (int kb = 0; kb < 11; ++kb) {
        if (kb == 10)     WAIT_VM0;     // tail: this slab's own loads must land
        else if (kb > 0)  WAIT_VM6;     // steady: kb's triple landed, kb+1's in flight
        bf16x8 a[4];
        if (kb < 3) ldA4_rb(Rbu, lr, kb, lk8, a);
        else        ldA4_hb(Hb, lr, kb-3, lk8, a);
        const char* bb = ring + (kb&1)*6144;
        bf16x8 br[2], bz[2], bg[2];
        #pragma unroll
        for (int j = 0; j < 2; ++j) {
            br[j] = rdW2(bb,        j*16 + lr, lk);
            bz[j] = rdW2(bb + 2048, j*16 + lr, lk);
            bg[j] = rdW2(bb + 4096, j*16 + lr, lk);
        }
        WAIT_LGKM;                               // frags in regs; buf free for reuse
        if (kb + 2 <= 10) issue_triple(kb+2, ring + (kb&1)*6144);
        __builtin_amdgcn_s_setprio(1);
        #pragma unroll
        for (int j = 0; j < 2; ++j)
            #pragma unroll
            for (int i = 0; i < 4; ++i) {
                ar[i][j] = __builtin_amdgcn_mfma_f32_16x16x32_bf16(br[j], a[i], ar[i][j], 0,0,0);
                az[i][j] = __builtin_amdgcn_mfma_f32_16x16x32_bf16(bz[j], a[i], az[i][j], 0,0,0);
                ag[i][j] = __builtin_amdgcn_mfma_f32_16x16x32_bf16(bg[j], a[i], ag[i][j], 0,0,0);
            }
        __builtin_amdgcn_s_setprio(0);
        if (kb == 2) {   // gi complete -> pack with bias, reset ag for gh
            #pragma unroll
            for (int j = 0; j < 2; ++j) {
                const int c0 = cw + j*16 + lk*4;
                f32x4 b4 = *(const f32x4*)(b_ih + 512 + c0);
                #pragma unroll
                for (int i = 0; i < 4; ++i) {
                    gipk[i][j][0] = pk2(ag[i][j][0] + b4[0], ag[i][j][1] + b4[1]);
                    gipk[i][j][1] = pk2(ag[i][j][2] + b4[2], ag[i][j][3] + b4[3]);
                    ag[i][j] = (f32x4){0,0,0,0};
                }
            }
        }
    }
    __syncthreads();   // ALL waves done reading hx from Hb before anyone overwrites it

    // ---- GRU epilogue: h_new -> Hb (own cols) + global store ----
    #pragma unroll
    for (int j = 0; j < 2; ++j) {
        const int c0 = cw + j*16 + lk*4;
        f32x4 bir = *(const f32x4*)(b_ih + c0),       bhr = *(const f32x4*)(b_hh + c0);
        f32x4 biz = *(const f32x4*)(b_ih + 256 + c0), bhz = *(const f32x4*)(b_hh + 256 + c0);
        f32x4 bhn = *(const f32x4*)(b_hh + 512 + c0);
        #pragma unroll
        for (int i = 0; i < 4; ++i) {
            const int row = i*16 + lr;
            uint2 hxd = *(const uint2*)(Hb + swzb(row, c0));
            float hn4[4];
            #pragma unroll
            for (int e = 0; e < 4; ++e) {
                float rg = sigm(ar[i][j][e] + bir[e] + bhr[e]);
                float zg = sigm(az[i][j][e] + biz[e] + bhz[e]);
                float ng = tanh_(upk(gipk[i][j][e>>1], e&1) + rg*(ag[i][j][e] + bhn[e]));
                float hxv = upk(e < 2 ? hxd.x : hxd.y, e&1);
                hn4[e] = (1.0f - zg)*ng + zg*hxv;
            }
            uint2 o; o.x = pk2(hn4[0], hn4[1]); o.y = pk2(hn4[2], hn4[3]);
            *(uint2*)(Hb + swzb(row, c0)) = o;
            float4 st = { hn4[0], hn4[1], hn4[2], hn4[3] };
            *(float4*)(hout + (size_t)(row0+row)*256 + c0) = st;
        }
    }
    // prefetch f1 W1 kb0,kb1 into own ring (2KB entries)
    stage2k(ws + (size_t)33*8192 + w*1024, ring,        lane);
    stage2k(ws + (size_t)34*8192 + w*1024, ring + 2048, lane);
    __syncthreads();   // h_new visible; prefetch drained

    // ---- LayerNorm: Hb(h_new) -> Hb(h_ln), 8 thr/row in-wave reduce ----
    {
        const int row = tid >> 3;
        const int o   = tid & 7;
        bf16x8 ch[4];
        float sum = 0.0f, sq = 0.0f;
        #pragma unroll
        for (int jx = 0; jx < 4; ++jx) {
            ch[jx] = *(const bf16x8*)(Hb + swzb(row, o*32 + jx*8));
            #pragma unroll
            for (int e = 0; e < 8; ++e) {
                float f = b2f((ushort)ch[jx][e]);
                sum += f; sq += f*f;
            }
        }
        sum += __shfl_xor(sum, 1); sum += __shfl_xor(sum, 2); sum += __shfl_xor(sum, 4);
        sq  += __shfl_xor(sq, 1);  sq  += __shfl_xor(sq, 2);  sq  += __shfl_xor(sq, 4);
        float mu   = sum * (1.0f/256.0f);
        float rstd = rsqrtf(sq*(1.0f/256.0f) - mu*mu + 1e-5f);
        #pragma unroll
        for (int jx = 0; jx < 4; ++jx) {
            int col0 = o*32 + jx*8;
            float4 g0 = *(const float4*)(ln_g + col0), g1 = *(const float4*)(ln_g + col0 + 4);
            float4 bb0 = *(const float4*)(ln_b + col0), bb1 = *(const float4*)(ln_b + col0 + 4);
            bf16x8 oo;
            oo[0] = (short)f2bf((b2f((ushort)ch[jx][0]) - mu)*rstd*g0.x + bb0.x);
            oo[1] = (short)f2bf((b2f((ushort)ch[jx][1]) - mu)*rstd*g0.y + bb0.y);
            oo[2] = (short)f2bf((b2f((ushort)ch[jx][2]) - mu)*rstd*g0.z + bb0.z);
            oo[3] = (short)f2bf((b2f((ushort)ch[jx][3]) - mu)*rstd*g0.w + bb0.w);
            oo[4] = (short)f2bf((b2f((ushort)ch[jx][4]) - mu)*rstd*g1.x + bb1.x);
            oo[5] = (short)f2bf((b2f((ushort)ch[jx][5]) - mu)*rstd*g1.y + bb1.y);
            oo[6] = (short)f2bf((b2f((ushort)ch[jx][6]) - mu)*rstd*g1.z + bb1.z);
            oo[7] = (short)f2bf((b2f((ushort)ch[jx][7]) - mu)*rstd*g1.w + bb1.w);
            *(bf16x8*)(Hb + swzb(row, col0)) = oo;
        }
    }
    __syncthreads();

    // ---- f1: kb 0..7, barrier-free (A = Hb h_ln; B = own W1 cols) ----
    f32x4 c2[4][2];
    #pragma unroll
    for (int i = 0; i < 4; ++i)
        #pragma unroll
        for (int j = 0; j < 2; ++j) c2[i][j] = (f32x4){0,0,0,0};
    #pragma unroll
    for (int kb = 0; kb < 8; ++kb) {
        if (kb == 7)     WAIT_VM0;
        else if (kb > 0) WAIT_VM2;
        bf16x8 a[4];
        ldA4_hb(Hb, lr, kb, lk8, a);
        const char* bb = ring + (kb&1)*2048;
        bf16x8 b[2];
        #pragma unroll
        for (int j = 0; j < 2; ++j) b[j] = rdW2(bb, j*16 + lr, lk);
        WAIT_LGKM;
        if (kb + 2 <= 7) stage2k(ws + (size_t)(33+kb+2)*8192 + w*1024, ring + (kb&1)*2048, lane);
        __builtin_amdgcn_s_setprio(1);
        #pragma unroll
        for (int j = 0; j < 2; ++j)
            #pragma unroll
            for (int i = 0; i < 4; ++i)
                c2[i][j] = __builtin_amdgcn_mfma_f32_16x16x32_bf16(b[j], a[i], c2[i][j], 0,0,0);
        __builtin_amdgcn_s_setprio(0);
    }
    // prefetch f2 W2 kb0,kb1 (1KB entries)
    stage1k(ws + (size_t)41*8192 + 0*4096 + w*512, ring,        lane);
    stage1k(ws + (size_t)41*8192 + 1*4096 + w*512, ring + 1024, lane);
    __syncthreads();   // all h_ln reads done everywhere
    // write f1 over h_ln (own cols)
    #pragma unroll
    for (int j = 0; j < 2; ++j) {
        const int c0 = cw + j*16 + lk*4;
        f32x4 b4 = *(const f32x4*)(b1 + c0);
        #pragma unroll
        for (int i = 0; i < 4; ++i) {
            const int row = i*16 + lr;
            uint2 o;
            o.x = pk2(fmaxf(c2[i][j][0]+b4[0],0.f), fmaxf(c2[i][j][1]+b4[1],0.f));
            o.y = pk2(fmaxf(c2[i][j][2]+b4[2],0.f), fmaxf(c2[i][j][3]+b4[3],0.f));
            *(uint2*)(Hb + swzb(row, c0)) = o;
        }
    }
    __syncthreads();

    // ---- f2: kb 0..7, barrier-free (A = Hb f1; B = own 16 W2 cols) ----
    f32x4 c3[4];
    #pragma unroll
    for (int i = 0; i < 4; ++i) c3[i] = (f32x4){0,0,0,0};
    #pragma unroll
    for (int kb = 0; kb < 8; ++kb) {
        if (kb == 7)     WAIT_VM0;
        else if (kb > 0) WAIT_VM1;
        bf16x8 a[4];
        ldA4_hb(Hb, lr, kb, lk8, a);
        bf16x8 b = rdW2(ring + (kb&1)*1024, lr, lk);
        WAIT_LGKM;
        if (kb + 2 <= 7) {
            int k2 = kb + 2;
            stage1k(ws + (size_t)(41 + (k2>>1))*8192 + (k2&1)*4096 + w*512, ring + (kb&1)*1024, lane);
        }
        __builtin_amdgcn_s_setprio(1);
        #pragma unroll
        for (int i = 0; i < 4; ++i)
            c3[i] = __builtin_amdgcn_mfma_f32_16x16x32_bf16(b, a[i], c3[i], 0,0,0);
        __builtin_amdgcn_s_setprio(0);
    }
    // prefetch W3 kb0,kb1 (2KB entries)
    stage2k(ws + (size_t)45*8192 + w*1024, ring,        lane);
    stage2k(ws + (size_t)46*8192 + w*1024, ring + 2048, lane);
    __syncthreads();   // all f1 reads done
    // write F2 -> Hb linear [64][136]u16 (own 16 cols)
    ushort* F2 = (ushort*)Hb;
    {
        const int c0 = w*16 + lk*4;
        f32x4 b4 = *(const f32x4*)(b2 + c0);
        #pragma unroll
        for (int i = 0; i < 4; ++i) {
            const int row = i*16 + lr;
            uint2 o;
            o.x = pk2(fmaxf(c3[i][0]+b4[0],0.f), fmaxf(c3[i][1]+b4[1],0.f));
            o.y = pk2(fmaxf(c3[i][2]+b4[2],0.f), fmaxf(c3[i][3]+b4[3],0.f));
            *(uint2*)((char*)F2 + row*272 + c0*2) = o;
        }
    }
    __syncthreads();

    // ---- W3: kb 0..3, barrier-free (A = F2 linear; B = own 32 cols) + einsum ----
    {
        f32x4 c4[4][2];
        #pragma unroll
        for (int i = 0; i < 4; ++i)
            #pragma unroll
            for (int j = 0; j < 2; ++j) c4[i][j] = (f32x4){0,0,0,0};
        #pragma unroll
        for (int kb = 0; kb < 4; ++kb) {
            if (kb == 3)     WAIT_VM0;
            else if (kb > 0) WAIT_VM2;
            bf16x8 a[4];
            #pragma unroll
            for (int i = 0; i < 4; ++i)
                a[i] = *(const bf16x8*)((const char*)F2 + (i*16 + lr)*272 + (kb*32 + lk8)*2);
            const char* bb = ring + (kb&1)*2048;
            bf16x8 b[2];
            #pragma unroll
            for (int j = 0; j < 2; ++j) b[j] = rdW2(bb, j*16 + lr, lk);
            WAIT_LGKM;
            if (kb + 2 <= 3) stage2k(ws + (size_t)(45+kb+2)*8192 + w*1024, ring + (kb&1)*2048, lane);
            __builtin_amdgcn_s_setprio(1);
            #pragma unroll
            for (int j = 0; j < 2; ++j)
                #pragma unroll
                for (int i = 0; i < 4; ++i)
                    c4[i][j] = __builtin_amdgcn_mfma_f32_16x16x32_bf16(b[j], a[i], c4[i][j], 0,0,0);
            __builtin_amdgcn_s_setprio(0);
        }
        #pragma unroll
        for (int j = 0; j < 2; ++j)
            #pragma unroll
            for (int i = 0; i < 4; ++i) {
                const int row = i*16 + lr;
                #pragma unroll
                for (int e = 0; e < 4; ++e) {
                    int col = cw + j*16 + lk*4 + e;
                    if (col < 162) {
                        int s = col / 27, m = col - s*27;
                        float K = fminf(fmaxf(c4[i][j][e] + b3[col], -3.0f), 3.0f);
                        atomicAdd(&xmc[row*6 + s], K * b2f(Rbu[row*104 + m]));
                    }
                }
            }
    }
    __syncthreads();

    for (int t = tid; t < ROWS*6; t += NTHR) {
        int row = t / 6, s = t - row*6;
        float v = fminf(fmaxf(xmc[t], -5.0f), 5.0f);
        out[(size_t)(row0+row)*6 + s] = v;
    }
}

extern "C" void kernel_launch(void* const* d_in, const int* in_sizes, int n_in,
                              void* d_out, int out_size, void* d_ws, size_t ws_size,
                              hipStream_t stream) {
    const float* meas      = (const float*)d_in[0];
    const float* mask      = (const float*)d_in[1];
    const float* dtv       = (const float*)d_in[2];
    const float* baselines = (const float*)d_in[3];
    const float* x_prev    = (const float*)d_in[4];
    const float* hx        = (const float*)d_in[5];
    const float* W_ih      = (const float*)d_in[6];
    const float* W_hh      = (const float*)d_in[7];
    const float* b_ih      = (const float*)d_in[8];
    const float* b_hh      = (const float*)d_in[9];
    const float* ln_g      = (const float*)d_in[10];
    const float* ln_b      = (const float*)d_in[11];
    const float* W1        = (const float*)d_in[12];
    const float* b1        = (const float*)d_in[13];
    const float* W2        = (const float*)d_in[14];
    const float* b2        = (const float*)d_in[15];
    const float* W3        = (const float*)d_in[16];
    const float* b3        = (const float*)d_in[17];
    ushort* wsb = (ushort*)d_ws;
    float* outp = (float*)d_out;

    prep_weights<<<(W_TOTAL + 255)/256, 256, 0, stream>>>(W_ih, W_hh, W1, W2, W3, wsb);
    knet_mfma<<<NWG, NTHR, LDS_TOTAL, stream>>>(
        meas, mask, dtv, baselines, x_prev, hx,
        b_ih, b_hh, ln_g, ln_b, b1, b2, b3, wsb, outp);
}